// Round 12
// baseline (153.138 us; speedup 1.0000x reference)
//
#include <hip/hip_runtime.h>
#include <hip/hip_bf16.h>
#include <stdint.h>

// Problem constants
#define B_    64
#define N_    197
#define C_    768
#define H_    12
#define HD_   64
#define M_    (B_ * N_)     // 12608
#define MPAD  12672         // 99 * 128
#define KP_   224           // padded key-dim stride for V^T (global)
#define VS_   232           // V^T row stride in LDS (29 granules -> 2-way-free)
#define LOG2E 1.44269504f
#define QSCALE_ (0.125f * LOG2E)   // 64^-0.5 folded with log2e (softmax uses exp2)

typedef unsigned short u16;
typedef __attribute__((ext_vector_type(8))) __bf16 bf16x8;
typedef __attribute__((ext_vector_type(4))) float  f32x4;

__device__ __forceinline__ u16 f2bf(float f) {
  union { float f; uint32_t u; } v; v.f = f;
  uint32_t r = (v.u + 0x7FFFu + ((v.u >> 16) & 1u)) >> 16;
  return (u16)r;
}
__device__ __forceinline__ float bf2f(u16 u) {
  union { uint32_t u; float f; } v; v.u = ((uint32_t)u) << 16;
  return v.f;
}

// bijective XCD-chunked swizzle (m204): consecutive wgids land on one XCD.
__device__ __forceinline__ int xcd_swz(int orig, int nwg) {
  int q = nwg >> 3, r = nwg & 7;
  int xcd = orig & 7, idx = orig >> 3;
  int base = (xcd < r) ? xcd * (q + 1) : r * (q + 1) + (xcd - r) * q;
  return base + idx;
}

// async global->LDS 16B copy. Dest must be wave-base + lane*16 (linear).
#define GLDS(g, l)                                                             \
  __builtin_amdgcn_global_load_lds(                                            \
      (const __attribute__((address_space(1))) void*)(g),                      \
      (__attribute__((address_space(3))) void*)(l), 16, 0, 0)

// ---------------------------------------------------------------- converts
__global__ __launch_bounds__(256) void k_convert_x(const float* __restrict__ src,
                                                   u16* __restrict__ dst) {
  int i = blockIdx.x * 256 + threadIdx.x;   // 8 elems per thread
  size_t e = (size_t)i * 8;
  uint4 o;
  if (e < (size_t)M_ * C_) {
    const float4* s4 = (const float4*)(src + e);
    float4 a = s4[0], b = s4[1];
    o.x = (uint32_t)f2bf(a.x) | ((uint32_t)f2bf(a.y) << 16);
    o.y = (uint32_t)f2bf(a.z) | ((uint32_t)f2bf(a.w) << 16);
    o.z = (uint32_t)f2bf(b.x) | ((uint32_t)f2bf(b.y) << 16);
    o.w = (uint32_t)f2bf(b.z) | ((uint32_t)f2bf(b.w) << 16);
  } else {
    o.x = o.y = o.z = o.w = 0u;
  }
  *(uint4*)(dst + e) = o;
}

__global__ __launch_bounds__(256) void k_convert(const float* __restrict__ src,
                                                 u16* __restrict__ dst, int n8) {
  int i = blockIdx.x * 256 + threadIdx.x;
  if (i >= n8) return;
  size_t e = (size_t)i * 8;
  const float4* s4 = (const float4*)(src + e);
  float4 a = s4[0], b = s4[1];
  uint4 o;
  o.x = (uint32_t)f2bf(a.x) | ((uint32_t)f2bf(a.y) << 16);
  o.y = (uint32_t)f2bf(a.z) | ((uint32_t)f2bf(a.w) << 16);
  o.z = (uint32_t)f2bf(b.x) | ((uint32_t)f2bf(b.y) << 16);
  o.w = (uint32_t)f2bf(b.z) | ((uint32_t)f2bf(b.w) << 16);
  *(uint4*)(dst + e) = o;
}

// ------------------------------------------------------- rel-pos bias gather
// bias pre-scaled by log2e (softmax uses exp2)
__global__ __launch_bounds__(256) void k_bias(const float* __restrict__ rel,
                                              const int* __restrict__ idx,
                                              u16* __restrict__ biasb) {
  int h = blockIdx.y;
  int i = blockIdx.x * 256 + threadIdx.x;
  if (i >= 196 * 208) return;
  int qi1 = i / 208, colk = i - qi1 * 208;
  float v = 0.f;
  if (colk >= 1 && colk <= 196)
    v = rel[h * 729 + idx[qi1 * 196 + (colk - 1)]] * LOG2E;
  biasb[(size_t)h * 196 * 208 + i] = f2bf(v);
}

// ------------------------------------------------------------- qkv GEMM
// Proven 2-phase 128x128 structure (R7: 73.5 us, 607 TF).
#define STAGE2(SM, buf, kt, Ab, Bb)                                            \
  do {                                                                         \
    u16* As_ = (SM) + (buf) * 16384;                                           \
    u16* Bs_ = As_ + 8192;                                                     \
    _Pragma("unroll") for (int r_ = 0; r_ < 4; ++r_) {                         \
      int c_ = r_ * 256 + t;                                                   \
      int row_ = c_ >> 3, sl_ = c_ & 7, p_ = sl_ ^ (row_ & 7);                 \
      GLDS((const char*)((Ab) + (size_t)row_ * 768 + (kt) * 64) + p_ * 16,     \
           (char*)As_ + c_ * 16);                                              \
      GLDS((const char*)((Bb) + (size_t)row_ * 768 + (kt) * 64) + p_ * 16,     \
           (char*)Bs_ + c_ * 16);                                              \
    }                                                                          \
  } while (0)

__global__ __launch_bounds__(256) void k_gemm_qkv(
    const u16* __restrict__ A, const u16* __restrict__ Bt,
    const float* __restrict__ bias,
    u16* __restrict__ qb, u16* __restrict__ kb, u16* __restrict__ vtb) {
  __shared__ u16 SMEM[32768];               // 64 KiB: 2 x (As 16K + Bs 16K)
  const int t = threadIdx.x, lane = t & 63;
  const int w = t >> 6;
  const int wr = (w >> 1) * 64, wc = (w & 1) * 64;
  const int wg = xcd_swz(blockIdx.x, 99 * 18);
  const int tm = wg / 18, tn = wg % 18;
  const int rowg = lane >> 4, col16 = lane & 15;

  f32x4 acc[4][4] = {};
  const u16* Abase = A + (size_t)tm * 128 * 768;
  const u16* Bbase = Bt + (size_t)tn * 128 * 768;

  STAGE2(SMEM, 0, 0, Abase, Bbase);
  __syncthreads();
  int cur = 0;
  for (int kt = 1; kt <= 12; ++kt) {
    if (kt < 12) STAGE2(SMEM, cur ^ 1, kt, Abase, Bbase);
    const u16* As_ = SMEM + cur * 16384;
    const u16* Bs_ = As_ + 8192;
#pragma unroll
    for (int kk = 0; kk < 2; ++kk) {
      bf16x8 af[4], bfr[4];
      int q = kk * 4 + rowg;
#pragma unroll
      for (int mi = 0; mi < 4; ++mi) {
        int row = wr + mi * 16 + col16;
        af[mi] = *(const bf16x8*)((const char*)As_ + row * 128 + ((q ^ (row & 7)) * 16));
      }
#pragma unroll
      for (int ni = 0; ni < 4; ++ni) {
        int row = wc + ni * 16 + col16;
        bfr[ni] = *(const bf16x8*)((const char*)Bs_ + row * 128 + ((q ^ (row & 7)) * 16));
      }
#pragma unroll
      for (int mi = 0; mi < 4; ++mi)
#pragma unroll
        for (int ni = 0; ni < 4; ++ni)
          acc[mi][ni] = __builtin_amdgcn_mfma_f32_16x16x32_bf16(af[mi], bfr[ni], acc[mi][ni], 0, 0, 0);
    }
    __syncthreads();
    cur ^= 1;
  }

  if (tn < 12) {
    u16* dst = (tn < 6) ? qb : kb;
    const float scl = (tn < 6) ? QSCALE_ : 1.f;
    const int colbase = tn * 128 - ((tn < 6) ? 0 : 768);
#pragma unroll
    for (int mi = 0; mi < 4; ++mi) {
#pragma unroll
      for (int r = 0; r < 4; ++r) {
        int gm = tm * 128 + wr + mi * 16 + rowg * 4 + r;
        if (gm >= M_) continue;
        int bb = gm / 197, nn = gm - bb * 197;
#pragma unroll
        for (int ni = 0; ni < 4; ++ni) {
          int n = wc + ni * 16 + col16;
          int rem = colbase + n;
          int hh = rem >> 6, hd = rem & 63;
          float v = (acc[mi][ni][r] + bias[tn * 128 + n]) * scl;
          dst[((size_t)(bb * 12 + hh) * 197 + nn) * 64 + hd] = f2bf(v);
        }
      }
    }
  } else {
    u16* T = SMEM;                          // [128][128] u16, XOR-swizzled
#pragma unroll
    for (int mi = 0; mi < 4; ++mi)
#pragma unroll
      for (int r = 0; r < 4; ++r) {
        int m = wr + mi * 16 + rowg * 4 + r;
#pragma unroll
        for (int ni = 0; ni < 4; ++ni) {
          int n = wc + ni * 16 + col16;
          float v = acc[mi][ni][r] + bias[tn * 128 + n];
          T[n * 128 + (m ^ ((n & 7) << 3))] = f2bf(v);
        }
      }
    __syncthreads();
    const int l = t & 15, g = t >> 4;
#pragma unroll
    for (int p = 0; p < 8; ++p) {
      int n = p * 16 + g;
      int rem = tn * 128 + n - 1536;
      int hh = rem >> 6, hd = rem & 63;
#pragma unroll
      for (int i = 0; i < 8; ++i) {
        int m = i * 16 + l;
        int gm = tm * 128 + m;
        if (gm >= M_) continue;
        int bb = gm / 197, nn = gm - bb * 197;
        u16 val = T[n * 128 + (m ^ ((n & 7) << 3))];
        vtb[((size_t)((bb * 12 + hh) * 64 + hd)) * KP_ + nn] = val;
      }
    }
  }
}

// ------------------------------------------------------------- attention
// Persistent-block pipeline: 256 blocks (exactly 1/CU, zero tail), each
// handles 3 (b,h) pairs with double-buffered K/V LDS. stage(bh_{i+1}) is
// issued BEFORE compute(bh_i), so staging latency hides under compute for
// all but the first head. 8 waves consume 13 q-tiles per head (wave w takes
// tiles w and w+8), barrier-free inside compute. LDS = 2x(K 26.6 + V 29.7)
// + P 20.5 = 133 KB (precedent: 131 KB static worked in R8-R10).
__global__ __launch_bounds__(512) void k_attn(
    const u16* __restrict__ qb, const u16* __restrict__ kb,
    const u16* __restrict__ vtb, const u16* __restrict__ biasb,
    u16* __restrict__ ob) {
  __shared__ u16 Ks[2][208 * 64];           // 53.2 KB
  __shared__ u16 Vs[2][64 * VS_];           // 59.4 KB
  __shared__ u16 Ps[8][2][16 * 40];         // 20.5 KB
  const int t = threadIdx.x, lane = t & 63, w = t >> 6;
  const int rowg = lane >> 4, col16 = lane & 15;
  const int b3 = blockIdx.x * 3;

  // stage K (XOR-swizzled source) + V^T (stride 224 -> 232) for one head
#define STAGEKV(buf, bh)                                                       \
  do {                                                                         \
    const u16* kb_ = kb + (size_t)(bh) * 197 * 64;                             \
    const u16* vb_ = vtb + (size_t)(bh) * 64 * KP_;                            \
    _Pragma("unroll") for (int i_ = 0; i_ < 4; ++i_) {                         \
      int c_ = i_ * 512 + t;                                                   \
      if (c_ < 1664) {                                                         \
        int row_ = c_ >> 3, sl_ = c_ & 7, p_ = sl_ ^ (row_ & 7);               \
        GLDS((const char*)(kb_ + row_ * 64 + p_ * 8),                          \
             (char*)Ks[buf] + c_ * 16);                                        \
      }                                                                        \
    }                                                                          \
    _Pragma("unroll") for (int i_ = 0; i_ < 4; ++i_) {                         \
      int c_ = i_ * 512 + t;                                                   \
      if (c_ < 1856) {                                                         \
        int vr_ = c_ / 29, g_ = c_ - vr_ * 29;                                 \
        GLDS((const char*)(vb_ + vr_ * 224 + g_ * 8),                          \
             (char*)Vs[buf] + c_ * 16);                                        \
      }                                                                        \
    }                                                                          \
  } while (0)

  // zero V pad keys 197..223 (global pads are garbage; NaN-safety)
#define PADZERO(buf)                                                           \
  do {                                                                         \
    int row_ = t >> 3, j_ = t & 7;                                             \
    if (j_ < 6) {                                                              \
      uint2 z_; z_.x = 0u; z_.y = 0u;                                          \
      *(uint2*)(Vs[buf] + row_ * VS_ + 200 + j_ * 4) = z_;                     \
    }                                                                          \
    if (t < 192) {                                                             \
      int r2_ = t / 3, e_ = t - r2_ * 3;                                       \
      Vs[buf][r2_ * VS_ + 197 + e_] = 0;                                       \
    }                                                                          \
  } while (0)

  auto compute = [&](int buf, int bh) {
    const int hh = bh % 12, bb = bh / 12;
    const u16* qbase = qb + (size_t)bh * 197 * 64;
    const u16* Ksb = Ks[buf];
    const u16* Vsb = Vs[buf];
    for (int pass = 0; pass < 2; ++pass) {
      const int qt = w + pass * 8;
      if (qt > 12) break;                   // no barriers below: divergence OK
      const int q0 = qt * 16;
      const int qi = q0 + col16;

      bf16x8 qa0 = *(const bf16x8*)(qbase + (size_t)qi * 64 + rowg * 8);
      bf16x8 qa1 = *(const bf16x8*)(qbase + (size_t)qi * 64 + 32 + rowg * 8);

      const bool doB = (qi >= 1) && (qi < 197);
      const float bm = doB ? 1.f : 0.f;
      const u16* brow = biasb + ((size_t)hh * 196 + (doB ? qi - 1 : 0)) * 208;

      // QK^T + bias + running max (K from LDS)
      f32x4 sv[13];
      float mx = -1e38f;
#pragma unroll
      for (int nj = 0; nj < 13; ++nj) {
        int rk = nj * 16 + col16;
        const char* kp = (const char*)Ksb + rk * 128;
        bf16x8 a0 = *(const bf16x8*)(kp + ((rowg ^ (rk & 7)) * 16));
        bf16x8 a1 = *(const bf16x8*)(kp + (((rowg + 4) ^ (rk & 7)) * 16));
        f32x4 s = {0.f, 0.f, 0.f, 0.f};
        s = __builtin_amdgcn_mfma_f32_16x16x32_bf16(a0, qa0, s, 0, 0, 0);
        s = __builtin_amdgcn_mfma_f32_16x16x32_bf16(a1, qa1, s, 0, 0, 0);
        ushort4 bu = *(const ushort4*)(brow + nj * 16 + rowg * 4);
        float s0 = fmaf(bf2f(bu.x), bm, s[0]);
        float s1 = fmaf(bf2f(bu.y), bm, s[1]);
        float s2 = fmaf(bf2f(bu.z), bm, s[2]);
        float s3 = fmaf(bf2f(bu.w), bm, s[3]);
        if (nj == 12) {                      // keys 192..207: mask >=197
          if (192 + rowg * 4 + 0 >= 197) s0 = -1e38f;
          if (192 + rowg * 4 + 1 >= 197) s1 = -1e38f;
          if (192 + rowg * 4 + 2 >= 197) s2 = -1e38f;
          if (192 + rowg * 4 + 3 >= 197) s3 = -1e38f;
        }
        sv[nj][0] = s0; sv[nj][1] = s1; sv[nj][2] = s2; sv[nj][3] = s3;
        mx = fmaxf(fmaxf(mx, fmaxf(s0, s1)), fmaxf(s2, s3));
      }
      mx = fmaxf(mx, __shfl_xor(mx, 16));
      mx = fmaxf(mx, __shfl_xor(mx, 32));

      float sm = 0.f;
#pragma unroll
      for (int nj = 0; nj < 13; ++nj)
#pragma unroll
        for (int r = 0; r < 4; ++r) {
          float p = exp2f(sv[nj][r] - mx);
          sv[nj][r] = p;
          sm += p;
        }
      sm += __shfl_xor(sm, 16);
      sm += __shfl_xor(sm, 32);
      float inv = 1.f / sm;

      // normalize + pack P via v_cvt_pk_bf16_f32
      uint2 pk[13];
#pragma unroll
      for (int nj = 0; nj < 13; ++nj) {
        float n0 = sv[nj][0] * inv, n1 = sv[nj][1] * inv;
        float n2 = sv[nj][2] * inv, n3 = sv[nj][3] * inv;
        uint32_t lo, hi;
        asm("v_cvt_pk_bf16_f32 %0, %1, %2" : "=v"(lo) : "v"(n0), "v"(n1));
        asm("v_cvt_pk_bf16_f32 %0, %1, %2" : "=v"(hi) : "v"(n2), "v"(n3));
        pk[nj].x = lo; pk[nj].y = hi;
      }

      // PV: 7 chunks of 32 keys; P double-slot LDS transpose; V from LDS
      u16* pw0 = Ps[w][0];
      u16* pw1 = Ps[w][1];
      uint2 z2; z2.x = 0u; z2.y = 0u;

      *(uint2*)(pw0 + col16 * 40 + rowg * 4) = pk[0];
      *(uint2*)(pw0 + col16 * 40 + 16 + rowg * 4) = pk[1];
      bf16x8 pa = *(const bf16x8*)(pw0 + col16 * 40 + rowg * 8);

      bf16x8 vb[2][4];
#pragma unroll
      for (int dt = 0; dt < 4; ++dt)
        vb[0][dt] = *(const bf16x8*)(Vsb + (dt * 16 + col16) * VS_ + rowg * 8);

      f32x4 oa[4] = {};
#pragma unroll
      for (int c = 0; c < 7; ++c) {
        if (c < 6) {
#pragma unroll
          for (int dt = 0; dt < 4; ++dt)
            vb[(c + 1) & 1][dt] = *(const bf16x8*)(Vsb + (dt * 16 + col16) * VS_ + (c + 1) * 32 + rowg * 8);
          u16* pwn = ((c + 1) & 1) ? pw1 : pw0;
          *(uint2*)(pwn + col16 * 40 + rowg * 4) = pk[2 * c + 2];
          *(uint2*)(pwn + col16 * 40 + 16 + rowg * 4) = (c == 5) ? z2 : pk[2 * c + 3];
        }
#pragma unroll
        for (int dt = 0; dt < 4; ++dt)
          oa[dt] = __builtin_amdgcn_mfma_f32_16x16x32_bf16(pa, vb[c & 1][dt], oa[dt], 0, 0, 0);
        if (c < 6) {
          u16* pwn = ((c + 1) & 1) ? pw1 : pw0;
          pa = *(const bf16x8*)(pwn + col16 * 40 + rowg * 8);
        }
      }

#pragma unroll
      for (int dt = 0; dt < 4; ++dt) {
#pragma unroll
        for (int r = 0; r < 4; ++r) {
          int qr = q0 + rowg * 4 + r;
          if (qr < 197)
            ob[((size_t)bb * 197 + qr) * 768 + hh * 64 + dt * 16 + col16] = f2bf(oa[dt][r]);
        }
      }
    }
  };

  // ---- pipeline: stage0 | {stage1 || compute0} | {stage2 || compute1} | compute2
  STAGEKV(0, b3);
  asm volatile("s_waitcnt vmcnt(0)" ::: "memory");
  __syncthreads();
  PADZERO(0);
  __syncthreads();

  STAGEKV(1, b3 + 1);
  compute(0, b3);
  asm volatile("s_waitcnt vmcnt(0)" ::: "memory");
  __syncthreads();
  PADZERO(1);
  __syncthreads();

  STAGEKV(0, b3 + 2);
  compute(1, b3 + 1);
  asm volatile("s_waitcnt vmcnt(0)" ::: "memory");
  __syncthreads();
  PADZERO(0);
  __syncthreads();

  compute(0, b3 + 2);
#undef STAGEKV
#undef PADZERO
}

// ------------------------------------------------------------- proj GEMM
__global__ __launch_bounds__(256) void k_gemm_proj(
    const u16* __restrict__ A, const u16* __restrict__ Bt,
    const float* __restrict__ bias, float* __restrict__ out) {
  __shared__ u16 SMEM[32768];
  const int t = threadIdx.x, lane = t & 63;
  const int w = t >> 6;
  const int wr = (w >> 1) * 64, wc = (w & 1) * 64;
  const int wg = xcd_swz(blockIdx.x, 99 * 6);
  const int tm = wg / 6, tn = wg % 6;
  const int rowg = lane >> 4, col16 = lane & 15;

  f32x4 acc[4][4] = {};
  const u16* Abase = A + (size_t)tm * 128 * 768;
  const u16* Bbase = Bt + (size_t)tn * 128 * 768;

  STAGE2(SMEM, 0, 0, Abase, Bbase);
  __syncthreads();
  int cur = 0;
  for (int kt = 1; kt <= 12; ++kt) {
    if (kt < 12) STAGE2(SMEM, cur ^ 1, kt, Abase, Bbase);
    const u16* As_ = SMEM + cur * 16384;
    const u16* Bs_ = As_ + 8192;
#pragma unroll
    for (int kk = 0; kk < 2; ++kk) {
      bf16x8 af[4], bfr[4];
      int q = kk * 4 + rowg;
#pragma unroll
      for (int mi = 0; mi < 4; ++mi) {
        int row = wr + mi * 16 + col16;
        af[mi] = *(const bf16x8*)((const char*)As_ + row * 128 + ((q ^ (row & 7)) * 16));
      }
#pragma unroll
      for (int ni = 0; ni < 4; ++ni) {
        int row = wc + ni * 16 + col16;
        bfr[ni] = *(const bf16x8*)((const char*)Bs_ + row * 128 + ((q ^ (row & 7)) * 16));
      }
#pragma unroll
      for (int mi = 0; mi < 4; ++mi)
#pragma unroll
        for (int ni = 0; ni < 4; ++ni)
          acc[mi][ni] = __builtin_amdgcn_mfma_f32_16x16x32_bf16(af[mi], bfr[ni], acc[mi][ni], 0, 0, 0);
    }
    __syncthreads();
    cur ^= 1;
  }

#pragma unroll
  for (int mi = 0; mi < 4; ++mi) {
#pragma unroll
    for (int r = 0; r < 4; ++r) {
      int gm = tm * 128 + wr + mi * 16 + rowg * 4 + r;
      if (gm >= M_) continue;
#pragma unroll
      for (int ni = 0; ni < 4; ++ni) {
        int gn = tn * 128 + wc + ni * 16 + col16;
        out[(size_t)gm * 768 + gn] = acc[mi][ni][r] + bias[gn];
      }
    }
  }
}

// ------------------------------------------------------------------ launch
extern "C" void kernel_launch(void* const* d_in, const int* in_sizes, int n_in,
                              void* d_out, int out_size, void* d_ws, size_t ws_size,
                              hipStream_t stream) {
  const float* x      = (const float*)d_in[0];
  const float* qkv_w  = (const float*)d_in[1];
  const float* qkv_b  = (const float*)d_in[2];
  const float* proj_w = (const float*)d_in[3];
  const float* proj_b = (const float*)d_in[4];
  const float* relpos = (const float*)d_in[5];
  const int*   rpidx  = (const int*)d_in[6];
  float* out = (float*)d_out;

  char* ws = (char*)d_ws;
  u16*   x16  = (u16*)(ws);                    // 19,464,192 B  [MPAD][768]
  u16*   wq16 = (u16*)(ws + 19464192);         //  3,538,944 B  [2304][768]
  u16*   wp16 = (u16*)(ws + 23003136);         //  1,179,648 B  [768][768]
  u16*   bb16 = (u16*)(ws + 24182784);         //    978,432 B  [12][196][208] bf16 (pre-scaled by log2e)
  u16*   q16  = (u16*)(ws + 25161216);         // 19,365,888 B  [B*H][197][64]
  u16*   k16  = (u16*)(ws + 44527104);         // 19,365,888 B  [B*H][197][64]
  u16*   vt16 = (u16*)(ws + 63892992);         // 22,020,096 B  [B*H][64][KP_]
  u16*   ao16 = (u16*)(ws + 85913088);         // 19,464,192 B  [MPAD][768]
  // total 105,377,280 B
  // vt16 pad keys (>=197) are never initialized: k_attn stages V into LDS
  // and zeroes pad keys there, so garbage pad memory is never consumed.

  k_convert_x<<<4752, 256, 0, stream>>>(x, x16);
  k_convert<<<864, 256, 0, stream>>>(qkv_w, wq16, 221184);
  k_convert<<<288, 256, 0, stream>>>(proj_w, wp16, 73728);
  k_bias<<<dim3(160, 12), 256, 0, stream>>>(relpos, rpidx, bb16);
  k_gemm_qkv<<<99 * 18, 256, 0, stream>>>(x16, wq16, qkv_b, q16, k16, vt16);
  k_attn<<<256, 512, 0, stream>>>(q16, k16, vt16, bb16, ao16);
  k_gemm_proj<<<99 * 6, 256, 0, stream>>>(ao16, wp16, proj_b, out);
}

// Round 13
// 147.129 us; speedup vs baseline: 1.0408x; 1.0408x over previous
//
#include <hip/hip_runtime.h>
#include <hip/hip_bf16.h>
#include <stdint.h>

// Problem constants
#define B_    64
#define N_    197
#define C_    768
#define H_    12
#define HD_   64
#define M_    (B_ * N_)     // 12608
#define MPAD  12672         // 99 * 128
#define KP_   224           // padded key-dim stride for V^T (global)
#define VS_   208           // V^T row stride in LDS (26 granules -> <=2-way, 62KB total)
#define LOG2E 1.44269504f
#define QSCALE_ (0.125f * LOG2E)   // 64^-0.5 folded with log2e (softmax uses exp2)

typedef unsigned short u16;
typedef __attribute__((ext_vector_type(8))) __bf16 bf16x8;
typedef __attribute__((ext_vector_type(4))) float  f32x4;

__device__ __forceinline__ u16 f2bf(float f) {
  union { float f; uint32_t u; } v; v.f = f;
  uint32_t r = (v.u + 0x7FFFu + ((v.u >> 16) & 1u)) >> 16;
  return (u16)r;
}
__device__ __forceinline__ float bf2f(u16 u) {
  union { uint32_t u; float f; } v; v.u = ((uint32_t)u) << 16;
  return v.f;
}

// bijective XCD-chunked swizzle (m204): consecutive wgids land on one XCD.
__device__ __forceinline__ int xcd_swz(int orig, int nwg) {
  int q = nwg >> 3, r = nwg & 7;
  int xcd = orig & 7, idx = orig >> 3;
  int base = (xcd < r) ? xcd * (q + 1) : r * (q + 1) + (xcd - r) * q;
  return base + idx;
}

// async global->LDS 16B copy. Dest must be wave-base + lane*16 (linear).
#define GLDS(g, l)                                                             \
  __builtin_amdgcn_global_load_lds(                                            \
      (const __attribute__((address_space(1))) void*)(g),                      \
      (__attribute__((address_space(3))) void*)(l), 16, 0, 0)

// ---------------------------------------------------------------- converts
__global__ __launch_bounds__(256) void k_convert_x(const float* __restrict__ src,
                                                   u16* __restrict__ dst) {
  int i = blockIdx.x * 256 + threadIdx.x;   // 8 elems per thread
  size_t e = (size_t)i * 8;
  uint4 o;
  if (e < (size_t)M_ * C_) {
    const float4* s4 = (const float4*)(src + e);
    float4 a = s4[0], b = s4[1];
    o.x = (uint32_t)f2bf(a.x) | ((uint32_t)f2bf(a.y) << 16);
    o.y = (uint32_t)f2bf(a.z) | ((uint32_t)f2bf(a.w) << 16);
    o.z = (uint32_t)f2bf(b.x) | ((uint32_t)f2bf(b.y) << 16);
    o.w = (uint32_t)f2bf(b.z) | ((uint32_t)f2bf(b.w) << 16);
  } else {
    o.x = o.y = o.z = o.w = 0u;
  }
  *(uint4*)(dst + e) = o;
}

__global__ __launch_bounds__(256) void k_convert(const float* __restrict__ src,
                                                 u16* __restrict__ dst, int n8) {
  int i = blockIdx.x * 256 + threadIdx.x;
  if (i >= n8) return;
  size_t e = (size_t)i * 8;
  const float4* s4 = (const float4*)(src + e);
  float4 a = s4[0], b = s4[1];
  uint4 o;
  o.x = (uint32_t)f2bf(a.x) | ((uint32_t)f2bf(a.y) << 16);
  o.y = (uint32_t)f2bf(a.z) | ((uint32_t)f2bf(a.w) << 16);
  o.z = (uint32_t)f2bf(b.x) | ((uint32_t)f2bf(b.y) << 16);
  o.w = (uint32_t)f2bf(b.z) | ((uint32_t)f2bf(b.w) << 16);
  *(uint4*)(dst + e) = o;
}

// ------------------------------------------------------- rel-pos bias gather
// bias pre-scaled by log2e (softmax uses exp2)
__global__ __launch_bounds__(256) void k_bias(const float* __restrict__ rel,
                                              const int* __restrict__ idx,
                                              u16* __restrict__ biasb) {
  int h = blockIdx.y;
  int i = blockIdx.x * 256 + threadIdx.x;
  if (i >= 196 * 208) return;
  int qi1 = i / 208, colk = i - qi1 * 208;
  float v = 0.f;
  if (colk >= 1 && colk <= 196)
    v = rel[h * 729 + idx[qi1 * 196 + (colk - 1)]] * LOG2E;
  biasb[(size_t)h * 196 * 208 + i] = f2bf(v);
}

// ------------------------------------------------------------- qkv GEMM
// Proven 2-phase 128x128 structure (R7: 73.5 us, 607 TF).
#define STAGE2(SM, buf, kt, Ab, Bb)                                            \
  do {                                                                         \
    u16* As_ = (SM) + (buf) * 16384;                                           \
    u16* Bs_ = As_ + 8192;                                                     \
    _Pragma("unroll") for (int r_ = 0; r_ < 4; ++r_) {                         \
      int c_ = r_ * 256 + t;                                                   \
      int row_ = c_ >> 3, sl_ = c_ & 7, p_ = sl_ ^ (row_ & 7);                 \
      GLDS((const char*)((Ab) + (size_t)row_ * 768 + (kt) * 64) + p_ * 16,     \
           (char*)As_ + c_ * 16);                                              \
      GLDS((const char*)((Bb) + (size_t)row_ * 768 + (kt) * 64) + p_ * 16,     \
           (char*)Bs_ + c_ * 16);                                              \
    }                                                                          \
  } while (0)

__global__ __launch_bounds__(256) void k_gemm_qkv(
    const u16* __restrict__ A, const u16* __restrict__ Bt,
    const float* __restrict__ bias,
    u16* __restrict__ qb, u16* __restrict__ kb, u16* __restrict__ vtb) {
  __shared__ u16 SMEM[32768];               // 64 KiB: 2 x (As 16K + Bs 16K)
  const int t = threadIdx.x, lane = t & 63;
  const int w = t >> 6;
  const int wr = (w >> 1) * 64, wc = (w & 1) * 64;
  const int wg = xcd_swz(blockIdx.x, 99 * 18);
  const int tm = wg / 18, tn = wg % 18;
  const int rowg = lane >> 4, col16 = lane & 15;

  f32x4 acc[4][4] = {};
  const u16* Abase = A + (size_t)tm * 128 * 768;
  const u16* Bbase = Bt + (size_t)tn * 128 * 768;

  STAGE2(SMEM, 0, 0, Abase, Bbase);
  __syncthreads();
  int cur = 0;
  for (int kt = 1; kt <= 12; ++kt) {
    if (kt < 12) STAGE2(SMEM, cur ^ 1, kt, Abase, Bbase);
    const u16* As_ = SMEM + cur * 16384;
    const u16* Bs_ = As_ + 8192;
#pragma unroll
    for (int kk = 0; kk < 2; ++kk) {
      bf16x8 af[4], bfr[4];
      int q = kk * 4 + rowg;
#pragma unroll
      for (int mi = 0; mi < 4; ++mi) {
        int row = wr + mi * 16 + col16;
        af[mi] = *(const bf16x8*)((const char*)As_ + row * 128 + ((q ^ (row & 7)) * 16));
      }
#pragma unroll
      for (int ni = 0; ni < 4; ++ni) {
        int row = wc + ni * 16 + col16;
        bfr[ni] = *(const bf16x8*)((const char*)Bs_ + row * 128 + ((q ^ (row & 7)) * 16));
      }
#pragma unroll
      for (int mi = 0; mi < 4; ++mi)
#pragma unroll
        for (int ni = 0; ni < 4; ++ni)
          acc[mi][ni] = __builtin_amdgcn_mfma_f32_16x16x32_bf16(af[mi], bfr[ni], acc[mi][ni], 0, 0, 0);
    }
    __syncthreads();
    cur ^= 1;
  }

  if (tn < 12) {
    u16* dst = (tn < 6) ? qb : kb;
    const float scl = (tn < 6) ? QSCALE_ : 1.f;
    const int colbase = tn * 128 - ((tn < 6) ? 0 : 768);
#pragma unroll
    for (int mi = 0; mi < 4; ++mi) {
#pragma unroll
      for (int r = 0; r < 4; ++r) {
        int gm = tm * 128 + wr + mi * 16 + rowg * 4 + r;
        if (gm >= M_) continue;
        int bb = gm / 197, nn = gm - bb * 197;
#pragma unroll
        for (int ni = 0; ni < 4; ++ni) {
          int n = wc + ni * 16 + col16;
          int rem = colbase + n;
          int hh = rem >> 6, hd = rem & 63;
          float v = (acc[mi][ni][r] + bias[tn * 128 + n]) * scl;
          dst[((size_t)(bb * 12 + hh) * 197 + nn) * 64 + hd] = f2bf(v);
        }
      }
    }
  } else {
    u16* T = SMEM;                          // [128][128] u16, XOR-swizzled
#pragma unroll
    for (int mi = 0; mi < 4; ++mi)
#pragma unroll
      for (int r = 0; r < 4; ++r) {
        int m = wr + mi * 16 + rowg * 4 + r;
#pragma unroll
        for (int ni = 0; ni < 4; ++ni) {
          int n = wc + ni * 16 + col16;
          float v = acc[mi][ni][r] + bias[tn * 128 + n];
          T[n * 128 + (m ^ ((n & 7) << 3))] = f2bf(v);
        }
      }
    __syncthreads();
    const int l = t & 15, g = t >> 4;
#pragma unroll
    for (int p = 0; p < 8; ++p) {
      int n = p * 16 + g;
      int rem = tn * 128 + n - 1536;
      int hh = rem >> 6, hd = rem & 63;
#pragma unroll
      for (int i = 0; i < 8; ++i) {
        int m = i * 16 + l;
        int gm = tm * 128 + m;
        if (gm >= M_) continue;
        int bb = gm / 197, nn = gm - bb * 197;
        u16 val = T[n * 128 + (m ^ ((n & 7) << 3))];
        vtb[((size_t)((bb * 12 + hh) * 64 + hd)) * KP_ + nn] = val;
      }
    }
  }
}

// ------------------------------------------------------------- attention
// R11 structure (one (b,h) per block, K/V staged once, 8 waves x 13 q-tiles)
// with LDS slimmed to 62 KB so TWO blocks co-reside per CU: block B's compute
// hides block A's staging drain. Diet: V stride 232->208 (26-granule stride,
// <=2-way), single-slot P staging (R6-proven), chunk-6 dead-lane zeros
// (R1-proven) instead of 224-key V rows.
__global__ __launch_bounds__(512) void k_attn(
    const u16* __restrict__ qb, const u16* __restrict__ kb,
    const u16* __restrict__ vtb, const u16* __restrict__ biasb,
    u16* __restrict__ ob) {
  __shared__ u16 Ks[208 * 64];              // 26.0 KB
  __shared__ u16 Vs[64 * VS_];              // 26.0 KB
  __shared__ u16 Ps[8][16 * 40];            // 10.0 KB   -> total 62 KB
  const int t = threadIdx.x, lane = t & 63, w = t >> 6;
  const int bh = xcd_swz(blockIdx.x, 768);
  const int hh = bh % 12, bb = bh / 12;
  const int rowg = lane >> 4, col16 = lane & 15;
  const u16* kbase = kb + (size_t)bh * 197 * 64;
  const u16* qbase = qb + (size_t)bh * 197 * 64;
  const u16* vbase = vtb + (size_t)bh * 64 * KP_;

  // ---- stage K: 208 rows x 8 granules, XOR-swizzled source ----
#pragma unroll
  for (int i = 0; i < 4; ++i) {
    int c = i * 512 + t;
    if (c < 1664) {
      int row = c >> 3, sl = c & 7, p = sl ^ (row & 7);
      GLDS((const char*)(kbase + row * 64 + p * 8), (char*)Ks + c * 16);
    }
  }
  // ---- stage V^T: 64 rows x 26 granules (keys 0..207), global stride 224 ----
#pragma unroll
  for (int i = 0; i < 4; ++i) {
    int c = i * 512 + t;
    if (c < 1664) {
      int vrow = c / 26, g = c - vrow * 26;
      GLDS((const char*)(vbase + vrow * 224 + g * 8), (char*)Vs + c * 16);
    }
  }
  asm volatile("s_waitcnt vmcnt(0)" ::: "memory");
  __syncthreads();
  // ---- zero V pad keys 197..207 (global pads are garbage; NaN-safety) ----
#pragma unroll
  for (int i = 0; i < 2; ++i) {
    int idx = i * 512 + t;
    if (idx < 704) {
      int r2 = idx / 11, e = idx - r2 * 11;
      Vs[r2 * VS_ + 197 + e] = 0;
    }
  }
  __syncthreads();

  // ---- per-wave q-tiles: w and w+8 (w<5) ----
  for (int pass = 0; pass < 2; ++pass) {
    const int qt = w + pass * 8;
    if (qt > 12) break;                     // no barriers below: divergence OK
    const int q0 = qt * 16;
    const int qi = q0 + col16;

    bf16x8 qa0 = *(const bf16x8*)(qbase + (size_t)qi * 64 + rowg * 8);
    bf16x8 qa1 = *(const bf16x8*)(qbase + (size_t)qi * 64 + 32 + rowg * 8);

    const bool doB = (qi >= 1) && (qi < 197);
    const float bm = doB ? 1.f : 0.f;
    const u16* brow = biasb + ((size_t)hh * 196 + (doB ? qi - 1 : 0)) * 208;

    // QK^T + bias + running max (K from LDS)
    f32x4 sv[13];
    float mx = -1e38f;
#pragma unroll
    for (int nj = 0; nj < 13; ++nj) {
      int rk = nj * 16 + col16;
      const char* kp = (const char*)Ks + rk * 128;
      bf16x8 a0 = *(const bf16x8*)(kp + ((rowg ^ (rk & 7)) * 16));
      bf16x8 a1 = *(const bf16x8*)(kp + (((rowg + 4) ^ (rk & 7)) * 16));
      f32x4 s = {0.f, 0.f, 0.f, 0.f};
      s = __builtin_amdgcn_mfma_f32_16x16x32_bf16(a0, qa0, s, 0, 0, 0);
      s = __builtin_amdgcn_mfma_f32_16x16x32_bf16(a1, qa1, s, 0, 0, 0);
      ushort4 bu = *(const ushort4*)(brow + nj * 16 + rowg * 4);
      float s0 = fmaf(bf2f(bu.x), bm, s[0]);
      float s1 = fmaf(bf2f(bu.y), bm, s[1]);
      float s2 = fmaf(bf2f(bu.z), bm, s[2]);
      float s3 = fmaf(bf2f(bu.w), bm, s[3]);
      if (nj == 12) {                        // keys 192..207: mask >=197
        if (192 + rowg * 4 + 0 >= 197) s0 = -1e38f;
        if (192 + rowg * 4 + 1 >= 197) s1 = -1e38f;
        if (192 + rowg * 4 + 2 >= 197) s2 = -1e38f;
        if (192 + rowg * 4 + 3 >= 197) s3 = -1e38f;
      }
      sv[nj][0] = s0; sv[nj][1] = s1; sv[nj][2] = s2; sv[nj][3] = s3;
      mx = fmaxf(fmaxf(mx, fmaxf(s0, s1)), fmaxf(s2, s3));
    }
    mx = fmaxf(mx, __shfl_xor(mx, 16));
    mx = fmaxf(mx, __shfl_xor(mx, 32));

    float sm = 0.f;
#pragma unroll
    for (int nj = 0; nj < 13; ++nj)
#pragma unroll
      for (int r = 0; r < 4; ++r) {
        float p = exp2f(sv[nj][r] - mx);
        sv[nj][r] = p;
        sm += p;
      }
    sm += __shfl_xor(sm, 16);
    sm += __shfl_xor(sm, 32);
    float inv = 1.f / sm;

    // normalize + pack P via v_cvt_pk_bf16_f32
    uint2 pk[13];
#pragma unroll
    for (int nj = 0; nj < 13; ++nj) {
      float n0 = sv[nj][0] * inv, n1 = sv[nj][1] * inv;
      float n2 = sv[nj][2] * inv, n3 = sv[nj][3] * inv;
      uint32_t lo, hi;
      asm("v_cvt_pk_bf16_f32 %0, %1, %2" : "=v"(lo) : "v"(n0), "v"(n1));
      asm("v_cvt_pk_bf16_f32 %0, %1, %2" : "=v"(hi) : "v"(n2), "v"(n3));
      pk[nj].x = lo; pk[nj].y = hi;
    }

    // PV: 7 chunks of 32 keys; single-slot P transpose; V from LDS;
    // chunk 6 dead lanes (keys >= 208) substituted with zeros.
    u16* pw = Ps[w];
    uint2 z2; z2.x = 0u; z2.y = 0u;
    union { uint32_t u[4]; bf16x8 v; } zz;
    zz.u[0] = zz.u[1] = zz.u[2] = zz.u[3] = 0u;
    const bf16x8 z8 = zz.v;

    f32x4 oa[4] = {};
#pragma unroll
    for (int c = 0; c < 7; ++c) {
      *(uint2*)(pw + col16 * 40 + rowg * 4) = pk[2 * c];
      *(uint2*)(pw + col16 * 40 + 16 + rowg * 4) = (c == 6) ? z2 : pk[2 * c + 1];
      bf16x8 pa = *(const bf16x8*)(pw + col16 * 40 + rowg * 8);
      const bool dead = (c == 6) && (rowg >= 2);
      const int ko = dead ? 0 : c * 32 + rowg * 8;
#pragma unroll
      for (int dt = 0; dt < 4; ++dt) {
        bf16x8 vbv = *(const bf16x8*)(Vs + (dt * 16 + col16) * VS_ + ko);
        if (dead) { vbv = z8; }
        oa[dt] = __builtin_amdgcn_mfma_f32_16x16x32_bf16(pa, vbv, oa[dt], 0, 0, 0);
      }
    }

#pragma unroll
    for (int dt = 0; dt < 4; ++dt) {
#pragma unroll
      for (int r = 0; r < 4; ++r) {
        int qr = q0 + rowg * 4 + r;
        if (qr < 197)
          ob[((size_t)bb * 197 + qr) * 768 + hh * 64 + dt * 16 + col16] = f2bf(oa[dt][r]);
      }
    }
  }
}

// ------------------------------------------------------------- proj GEMM
__global__ __launch_bounds__(256) void k_gemm_proj(
    const u16* __restrict__ A, const u16* __restrict__ Bt,
    const float* __restrict__ bias, float* __restrict__ out) {
  __shared__ u16 SMEM[32768];
  const int t = threadIdx.x, lane = t & 63;
  const int w = t >> 6;
  const int wr = (w >> 1) * 64, wc = (w & 1) * 64;
  const int wg = xcd_swz(blockIdx.x, 99 * 6);
  const int tm = wg / 6, tn = wg % 6;
  const int rowg = lane >> 4, col16 = lane & 15;

  f32x4 acc[4][4] = {};
  const u16* Abase = A + (size_t)tm * 128 * 768;
  const u16* Bbase = Bt + (size_t)tn * 128 * 768;

  STAGE2(SMEM, 0, 0, Abase, Bbase);
  __syncthreads();
  int cur = 0;
  for (int kt = 1; kt <= 12; ++kt) {
    if (kt < 12) STAGE2(SMEM, cur ^ 1, kt, Abase, Bbase);
    const u16* As_ = SMEM + cur * 16384;
    const u16* Bs_ = As_ + 8192;
#pragma unroll
    for (int kk = 0; kk < 2; ++kk) {
      bf16x8 af[4], bfr[4];
      int q = kk * 4 + rowg;
#pragma unroll
      for (int mi = 0; mi < 4; ++mi) {
        int row = wr + mi * 16 + col16;
        af[mi] = *(const bf16x8*)((const char*)As_ + row * 128 + ((q ^ (row & 7)) * 16));
      }
#pragma unroll
      for (int ni = 0; ni < 4; ++ni) {
        int row = wc + ni * 16 + col16;
        bfr[ni] = *(const bf16x8*)((const char*)Bs_ + row * 128 + ((q ^ (row & 7)) * 16));
      }
#pragma unroll
      for (int mi = 0; mi < 4; ++mi)
#pragma unroll
        for (int ni = 0; ni < 4; ++ni)
          acc[mi][ni] = __builtin_amdgcn_mfma_f32_16x16x32_bf16(af[mi], bfr[ni], acc[mi][ni], 0, 0, 0);
    }
    __syncthreads();
    cur ^= 1;
  }

#pragma unroll
  for (int mi = 0; mi < 4; ++mi) {
#pragma unroll
    for (int r = 0; r < 4; ++r) {
      int gm = tm * 128 + wr + mi * 16 + rowg * 4 + r;
      if (gm >= M_) continue;
#pragma unroll
      for (int ni = 0; ni < 4; ++ni) {
        int gn = tn * 128 + wc + ni * 16 + col16;
        out[(size_t)gm * 768 + gn] = acc[mi][ni][r] + bias[gn];
      }
    }
  }
}

// ------------------------------------------------------------------ launch
extern "C" void kernel_launch(void* const* d_in, const int* in_sizes, int n_in,
                              void* d_out, int out_size, void* d_ws, size_t ws_size,
                              hipStream_t stream) {
  const float* x      = (const float*)d_in[0];
  const float* qkv_w  = (const float*)d_in[1];
  const float* qkv_b  = (const float*)d_in[2];
  const float* proj_w = (const float*)d_in[3];
  const float* proj_b = (const float*)d_in[4];
  const float* relpos = (const float*)d_in[5];
  const int*   rpidx  = (const int*)d_in[6];
  float* out = (float*)d_out;

  char* ws = (char*)d_ws;
  u16*   x16  = (u16*)(ws);                    // 19,464,192 B  [MPAD][768]
  u16*   wq16 = (u16*)(ws + 19464192);         //  3,538,944 B  [2304][768]
  u16*   wp16 = (u16*)(ws + 23003136);         //  1,179,648 B  [768][768]
  u16*   bb16 = (u16*)(ws + 24182784);         //    978,432 B  [12][196][208] bf16 (pre-scaled by log2e)
  u16*   q16  = (u16*)(ws + 25161216);         // 19,365,888 B  [B*H][197][64]
  u16*   k16  = (u16*)(ws + 44527104);         // 19,365,888 B  [B*H][197][64]
  u16*   vt16 = (u16*)(ws + 63892992);         // 22,020,096 B  [B*H][64][KP_]
  u16*   ao16 = (u16*)(ws + 85913088);         // 19,464,192 B  [MPAD][768]
  // total 105,377,280 B
  // vt16 pad keys (>=197) are never initialized: k_attn stages V into LDS
  // (keys 0..207 only) and zeroes keys 197..207 there; keys >=208 are never
  // read (dead-lane substitution in the PV loop).

  k_convert_x<<<4752, 256, 0, stream>>>(x, x16);
  k_convert<<<864, 256, 0, stream>>>(qkv_w, wq16, 221184);
  k_convert<<<288, 256, 0, stream>>>(proj_w, wp16, 73728);
  k_bias<<<dim3(160, 12), 256, 0, stream>>>(relpos, rpidx, bb16);
  k_gemm_qkv<<<99 * 18, 256, 0, stream>>>(x16, wq16, qkv_b, q16, k16, vt16);
  k_attn<<<768, 512, 0, stream>>>(q16, k16, vt16, bb16, ao16);
  k_gemm_proj<<<99 * 6, 256, 0, stream>>>(ao16, wp16, proj_b, out);
}

// Round 14
// 142.465 us; speedup vs baseline: 1.0749x; 1.0327x over previous
//
#include <hip/hip_runtime.h>
#include <hip/hip_bf16.h>
#include <stdint.h>

// Problem constants
#define B_    64
#define N_    197
#define C_    768
#define H_    12
#define HD_   64
#define M_    (B_ * N_)     // 12608
#define MPAD  12672         // 99 * 128
#define KP_   224           // padded key-dim stride for V^T (global)
#define VS_   208           // V^T row stride in LDS (26 granules -> <=2-way)
#define LOG2E 1.44269504f
#define QSCALE_ (0.125f * LOG2E)   // 64^-0.5 folded with log2e (softmax uses exp2)

typedef unsigned short u16;
typedef __attribute__((ext_vector_type(8))) __bf16 bf16x8;
typedef __attribute__((ext_vector_type(4))) float  f32x4;

__device__ __forceinline__ u16 f2bf(float f) {
  union { float f; uint32_t u; } v; v.f = f;
  uint32_t r = (v.u + 0x7FFFu + ((v.u >> 16) & 1u)) >> 16;
  return (u16)r;
}
__device__ __forceinline__ float bf2f(u16 u) {
  union { uint32_t u; float f; } v; v.u = ((uint32_t)u) << 16;
  return v.f;
}

// bijective XCD-chunked swizzle (m204): consecutive wgids land on one XCD.
__device__ __forceinline__ int xcd_swz(int orig, int nwg) {
  int q = nwg >> 3, r = nwg & 7;
  int xcd = orig & 7, idx = orig >> 3;
  int base = (xcd < r) ? xcd * (q + 1) : r * (q + 1) + (xcd - r) * q;
  return base + idx;
}

// async global->LDS 16B copy. Dest must be wave-base + lane*16 (linear).
#define GLDS(g, l)                                                             \
  __builtin_amdgcn_global_load_lds(                                            \
      (const __attribute__((address_space(1))) void*)(g),                      \
      (__attribute__((address_space(3))) void*)(l), 16, 0, 0)

// --------------------------------------------------------------- fused prep
// One kernel replacing convert_x / convert_wq / convert_wp / bias-gather:
// all four are independent; fusing removes 3 launch serializations and lets
// the tails overlap. Block ranges: [0,4752) x-convert, [4752,5616) qkv_w,
// [5616,5904) proj_w, [5904,7824) bias gather.
__device__ __forceinline__ uint4 cvt8(const float* __restrict__ p) {
  const float4* s4 = (const float4*)p;
  float4 a = s4[0], b = s4[1];
  uint4 o;
  o.x = (uint32_t)f2bf(a.x) | ((uint32_t)f2bf(a.y) << 16);
  o.y = (uint32_t)f2bf(a.z) | ((uint32_t)f2bf(a.w) << 16);
  o.z = (uint32_t)f2bf(b.x) | ((uint32_t)f2bf(b.y) << 16);
  o.w = (uint32_t)f2bf(b.z) | ((uint32_t)f2bf(b.w) << 16);
  return o;
}

__global__ __launch_bounds__(256) void k_prep(
    const float* __restrict__ x, const float* __restrict__ qkv_w,
    const float* __restrict__ proj_w, const float* __restrict__ rel,
    const int* __restrict__ idx,
    u16* __restrict__ x16, u16* __restrict__ wq16, u16* __restrict__ wp16,
    u16* __restrict__ bb16) {
  const int b = blockIdx.x, t = threadIdx.x;
  if (b < 4752) {
    // x: fp32 -> bf16, rows >= 12608 zero-filled (out [MPAD][768])
    int i = b * 256 + t;
    size_t e = (size_t)i * 8;
    uint4 o;
    if (e < (size_t)M_ * C_) o = cvt8(x + e);
    else { o.x = o.y = o.z = o.w = 0u; }
    *(uint4*)(x16 + e) = o;
  } else if (b < 5616) {
    int i = (b - 4752) * 256 + t;
    if (i < 221184) { size_t e = (size_t)i * 8; *(uint4*)(wq16 + e) = cvt8(qkv_w + e); }
  } else if (b < 5904) {
    int i = (b - 5616) * 256 + t;
    if (i < 73728) { size_t e = (size_t)i * 8; *(uint4*)(wp16 + e) = cvt8(proj_w + e); }
  } else {
    // bias gather, pre-scaled by log2e: bb16[h][qi-1][colk], colk 0 & >=197 -> 0
    int j = b - 5904;                 // 0..1919
    int h = j / 160;
    int i = (j - h * 160) * 256 + t;
    if (i < 196 * 208) {
      int qi1 = i / 208, colk = i - qi1 * 208;
      float v = 0.f;
      if (colk >= 1 && colk <= 196)
        v = rel[h * 729 + idx[qi1 * 196 + (colk - 1)]] * LOG2E;
      bb16[(size_t)h * 196 * 208 + i] = f2bf(v);
    }
  }
}

// ------------------------------------------------------------- qkv GEMM
// Proven 2-phase 128x128 structure (R7: 73.5 us, 607 TF).
#define STAGE2(SM, buf, kt, Ab, Bb)                                            \
  do {                                                                         \
    u16* As_ = (SM) + (buf) * 16384;                                           \
    u16* Bs_ = As_ + 8192;                                                     \
    _Pragma("unroll") for (int r_ = 0; r_ < 4; ++r_) {                         \
      int c_ = r_ * 256 + t;                                                   \
      int row_ = c_ >> 3, sl_ = c_ & 7, p_ = sl_ ^ (row_ & 7);                 \
      GLDS((const char*)((Ab) + (size_t)row_ * 768 + (kt) * 64) + p_ * 16,     \
           (char*)As_ + c_ * 16);                                              \
      GLDS((const char*)((Bb) + (size_t)row_ * 768 + (kt) * 64) + p_ * 16,     \
           (char*)Bs_ + c_ * 16);                                              \
    }                                                                          \
  } while (0)

__global__ __launch_bounds__(256) void k_gemm_qkv(
    const u16* __restrict__ A, const u16* __restrict__ Bt,
    const float* __restrict__ bias,
    u16* __restrict__ qb, u16* __restrict__ kb, u16* __restrict__ vtb) {
  __shared__ u16 SMEM[32768];               // 64 KiB: 2 x (As 16K + Bs 16K)
  const int t = threadIdx.x, lane = t & 63;
  const int w = t >> 6;
  const int wr = (w >> 1) * 64, wc = (w & 1) * 64;
  const int wg = xcd_swz(blockIdx.x, 99 * 18);
  const int tm = wg / 18, tn = wg % 18;
  const int rowg = lane >> 4, col16 = lane & 15;

  f32x4 acc[4][4] = {};
  const u16* Abase = A + (size_t)tm * 128 * 768;
  const u16* Bbase = Bt + (size_t)tn * 128 * 768;

  STAGE2(SMEM, 0, 0, Abase, Bbase);
  __syncthreads();
  int cur = 0;
  for (int kt = 1; kt <= 12; ++kt) {
    if (kt < 12) STAGE2(SMEM, cur ^ 1, kt, Abase, Bbase);
    const u16* As_ = SMEM + cur * 16384;
    const u16* Bs_ = As_ + 8192;
#pragma unroll
    for (int kk = 0; kk < 2; ++kk) {
      bf16x8 af[4], bfr[4];
      int q = kk * 4 + rowg;
#pragma unroll
      for (int mi = 0; mi < 4; ++mi) {
        int row = wr + mi * 16 + col16;
        af[mi] = *(const bf16x8*)((const char*)As_ + row * 128 + ((q ^ (row & 7)) * 16));
      }
#pragma unroll
      for (int ni = 0; ni < 4; ++ni) {
        int row = wc + ni * 16 + col16;
        bfr[ni] = *(const bf16x8*)((const char*)Bs_ + row * 128 + ((q ^ (row & 7)) * 16));
      }
#pragma unroll
      for (int mi = 0; mi < 4; ++mi)
#pragma unroll
        for (int ni = 0; ni < 4; ++ni)
          acc[mi][ni] = __builtin_amdgcn_mfma_f32_16x16x32_bf16(af[mi], bfr[ni], acc[mi][ni], 0, 0, 0);
    }
    __syncthreads();
    cur ^= 1;
  }

  if (tn < 12) {
    u16* dst = (tn < 6) ? qb : kb;
    const float scl = (tn < 6) ? QSCALE_ : 1.f;
    const int colbase = tn * 128 - ((tn < 6) ? 0 : 768);
#pragma unroll
    for (int mi = 0; mi < 4; ++mi) {
#pragma unroll
      for (int r = 0; r < 4; ++r) {
        int gm = tm * 128 + wr + mi * 16 + rowg * 4 + r;
        if (gm >= M_) continue;
        int bb = gm / 197, nn = gm - bb * 197;
#pragma unroll
        for (int ni = 0; ni < 4; ++ni) {
          int n = wc + ni * 16 + col16;
          int rem = colbase + n;
          int hh = rem >> 6, hd = rem & 63;
          float v = (acc[mi][ni][r] + bias[tn * 128 + n]) * scl;
          dst[((size_t)(bb * 12 + hh) * 197 + nn) * 64 + hd] = f2bf(v);
        }
      }
    }
  } else {
    u16* T = SMEM;                          // [128][128] u16, XOR-swizzled
#pragma unroll
    for (int mi = 0; mi < 4; ++mi)
#pragma unroll
      for (int r = 0; r < 4; ++r) {
        int m = wr + mi * 16 + rowg * 4 + r;
#pragma unroll
        for (int ni = 0; ni < 4; ++ni) {
          int n = wc + ni * 16 + col16;
          float v = acc[mi][ni][r] + bias[tn * 128 + n];
          T[n * 128 + (m ^ ((n & 7) << 3))] = f2bf(v);
        }
      }
    __syncthreads();
    const int l = t & 15, g = t >> 4;
#pragma unroll
    for (int p = 0; p < 8; ++p) {
      int n = p * 16 + g;
      int rem = tn * 128 + n - 1536;
      int hh = rem >> 6, hd = rem & 63;
#pragma unroll
      for (int i = 0; i < 8; ++i) {
        int m = i * 16 + l;
        int gm = tm * 128 + m;
        if (gm >= M_) continue;
        int bb = gm / 197, nn = gm - bb * 197;
        u16 val = T[n * 128 + (m ^ ((n & 7) << 3))];
        vtb[((size_t)((bb * 12 + hh) * 64 + hd)) * KP_ + nn] = val;
      }
    }
  }
}

// ------------------------------------------------------------- attention
// R13 structure: one (b,h) per block, K/V staged once (62 KB LDS), 8 waves
// consume 13 q-tiles barrier-free.
__global__ __launch_bounds__(512) void k_attn(
    const u16* __restrict__ qb, const u16* __restrict__ kb,
    const u16* __restrict__ vtb, const u16* __restrict__ biasb,
    u16* __restrict__ ob) {
  __shared__ u16 Ks[208 * 64];              // 26.0 KB
  __shared__ u16 Vs[64 * VS_];              // 26.0 KB
  __shared__ u16 Ps[8][16 * 40];            // 10.0 KB   -> total 62 KB
  const int t = threadIdx.x, lane = t & 63, w = t >> 6;
  const int bh = xcd_swz(blockIdx.x, 768);
  const int hh = bh % 12, bb = bh / 12;
  const int rowg = lane >> 4, col16 = lane & 15;
  const u16* kbase = kb + (size_t)bh * 197 * 64;
  const u16* qbase = qb + (size_t)bh * 197 * 64;
  const u16* vbase = vtb + (size_t)bh * 64 * KP_;

  // ---- stage K: 208 rows x 8 granules, XOR-swizzled source ----
#pragma unroll
  for (int i = 0; i < 4; ++i) {
    int c = i * 512 + t;
    if (c < 1664) {
      int row = c >> 3, sl = c & 7, p = sl ^ (row & 7);
      GLDS((const char*)(kbase + row * 64 + p * 8), (char*)Ks + c * 16);
    }
  }
  // ---- stage V^T: 64 rows x 26 granules (keys 0..207), global stride 224 ----
#pragma unroll
  for (int i = 0; i < 4; ++i) {
    int c = i * 512 + t;
    if (c < 1664) {
      int vrow = c / 26, g = c - vrow * 26;
      GLDS((const char*)(vbase + vrow * 224 + g * 8), (char*)Vs + c * 16);
    }
  }
  asm volatile("s_waitcnt vmcnt(0)" ::: "memory");
  __syncthreads();
  // ---- zero V pad keys 197..207 (global pads are garbage; NaN-safety) ----
#pragma unroll
  for (int i = 0; i < 2; ++i) {
    int idx = i * 512 + t;
    if (idx < 704) {
      int r2 = idx / 11, e = idx - r2 * 11;
      Vs[r2 * VS_ + 197 + e] = 0;
    }
  }
  __syncthreads();

  // ---- per-wave q-tiles: w and w+8 (w<5) ----
  for (int pass = 0; pass < 2; ++pass) {
    const int qt = w + pass * 8;
    if (qt > 12) break;                     // no barriers below: divergence OK
    const int q0 = qt * 16;
    const int qi = q0 + col16;

    bf16x8 qa0 = *(const bf16x8*)(qbase + (size_t)qi * 64 + rowg * 8);
    bf16x8 qa1 = *(const bf16x8*)(qbase + (size_t)qi * 64 + 32 + rowg * 8);

    const bool doB = (qi >= 1) && (qi < 197);
    const float bm = doB ? 1.f : 0.f;
    const u16* brow = biasb + ((size_t)hh * 196 + (doB ? qi - 1 : 0)) * 208;

    // QK^T + bias + running max (K from LDS)
    f32x4 sv[13];
    float mx = -1e38f;
#pragma unroll
    for (int nj = 0; nj < 13; ++nj) {
      int rk = nj * 16 + col16;
      const char* kp = (const char*)Ks + rk * 128;
      bf16x8 a0 = *(const bf16x8*)(kp + ((rowg ^ (rk & 7)) * 16));
      bf16x8 a1 = *(const bf16x8*)(kp + (((rowg + 4) ^ (rk & 7)) * 16));
      f32x4 s = {0.f, 0.f, 0.f, 0.f};
      s = __builtin_amdgcn_mfma_f32_16x16x32_bf16(a0, qa0, s, 0, 0, 0);
      s = __builtin_amdgcn_mfma_f32_16x16x32_bf16(a1, qa1, s, 0, 0, 0);
      ushort4 bu = *(const ushort4*)(brow + nj * 16 + rowg * 4);
      float s0 = fmaf(bf2f(bu.x), bm, s[0]);
      float s1 = fmaf(bf2f(bu.y), bm, s[1]);
      float s2 = fmaf(bf2f(bu.z), bm, s[2]);
      float s3 = fmaf(bf2f(bu.w), bm, s[3]);
      if (nj == 12) {                        // keys 192..207: mask >=197
        if (192 + rowg * 4 + 0 >= 197) s0 = -1e38f;
        if (192 + rowg * 4 + 1 >= 197) s1 = -1e38f;
        if (192 + rowg * 4 + 2 >= 197) s2 = -1e38f;
        if (192 + rowg * 4 + 3 >= 197) s3 = -1e38f;
      }
      sv[nj][0] = s0; sv[nj][1] = s1; sv[nj][2] = s2; sv[nj][3] = s3;
      mx = fmaxf(fmaxf(mx, fmaxf(s0, s1)), fmaxf(s2, s3));
    }
    mx = fmaxf(mx, __shfl_xor(mx, 16));
    mx = fmaxf(mx, __shfl_xor(mx, 32));

    float sm = 0.f;
#pragma unroll
    for (int nj = 0; nj < 13; ++nj)
#pragma unroll
      for (int r = 0; r < 4; ++r) {
        float p = exp2f(sv[nj][r] - mx);
        sv[nj][r] = p;
        sm += p;
      }
    sm += __shfl_xor(sm, 16);
    sm += __shfl_xor(sm, 32);
    float inv = 1.f / sm;

    // normalize + pack P via v_cvt_pk_bf16_f32
    uint2 pk[13];
#pragma unroll
    for (int nj = 0; nj < 13; ++nj) {
      float n0 = sv[nj][0] * inv, n1 = sv[nj][1] * inv;
      float n2 = sv[nj][2] * inv, n3 = sv[nj][3] * inv;
      uint32_t lo, hi;
      asm("v_cvt_pk_bf16_f32 %0, %1, %2" : "=v"(lo) : "v"(n0), "v"(n1));
      asm("v_cvt_pk_bf16_f32 %0, %1, %2" : "=v"(hi) : "v"(n2), "v"(n3));
      pk[nj].x = lo; pk[nj].y = hi;
    }

    // PV: 7 chunks of 32 keys; single-slot P transpose; V from LDS;
    // chunk 6 dead lanes (keys >= 208) substituted with zeros.
    u16* pw = Ps[w];
    uint2 z2; z2.x = 0u; z2.y = 0u;
    union { uint32_t u[4]; bf16x8 v; } zz;
    zz.u[0] = zz.u[1] = zz.u[2] = zz.u[3] = 0u;
    const bf16x8 z8 = zz.v;

    f32x4 oa[4] = {};
#pragma unroll
    for (int c = 0; c < 7; ++c) {
      *(uint2*)(pw + col16 * 40 + rowg * 4) = pk[2 * c];
      *(uint2*)(pw + col16 * 40 + 16 + rowg * 4) = (c == 6) ? z2 : pk[2 * c + 1];
      bf16x8 pa = *(const bf16x8*)(pw + col16 * 40 + rowg * 8);
      const bool dead = (c == 6) && (rowg >= 2);
      const int ko = dead ? 0 : c * 32 + rowg * 8;
#pragma unroll
      for (int dt = 0; dt < 4; ++dt) {
        bf16x8 vbv = *(const bf16x8*)(Vs + (dt * 16 + col16) * VS_ + ko);
        if (dead) { vbv = z8; }
        oa[dt] = __builtin_amdgcn_mfma_f32_16x16x32_bf16(pa, vbv, oa[dt], 0, 0, 0);
      }
    }

#pragma unroll
    for (int dt = 0; dt < 4; ++dt) {
#pragma unroll
      for (int r = 0; r < 4; ++r) {
        int qr = q0 + rowg * 4 + r;
        if (qr < 197)
          ob[((size_t)bb * 197 + qr) * 768 + hh * 64 + dt * 16 + col16] = f2bf(oa[dt][r]);
      }
    }
  }
}

// ------------------------------------------------------------- proj GEMM
__global__ __launch_bounds__(256) void k_gemm_proj(
    const u16* __restrict__ A, const u16* __restrict__ Bt,
    const float* __restrict__ bias, float* __restrict__ out) {
  __shared__ u16 SMEM[32768];
  const int t = threadIdx.x, lane = t & 63;
  const int w = t >> 6;
  const int wr = (w >> 1) * 64, wc = (w & 1) * 64;
  const int wg = xcd_swz(blockIdx.x, 99 * 6);
  const int tm = wg / 6, tn = wg % 6;
  const int rowg = lane >> 4, col16 = lane & 15;

  f32x4 acc[4][4] = {};
  const u16* Abase = A + (size_t)tm * 128 * 768;
  const u16* Bbase = Bt + (size_t)tn * 128 * 768;

  STAGE2(SMEM, 0, 0, Abase, Bbase);
  __syncthreads();
  int cur = 0;
  for (int kt = 1; kt <= 12; ++kt) {
    if (kt < 12) STAGE2(SMEM, cur ^ 1, kt, Abase, Bbase);
    const u16* As_ = SMEM + cur * 16384;
    const u16* Bs_ = As_ + 8192;
#pragma unroll
    for (int kk = 0; kk < 2; ++kk) {
      bf16x8 af[4], bfr[4];
      int q = kk * 4 + rowg;
#pragma unroll
      for (int mi = 0; mi < 4; ++mi) {
        int row = wr + mi * 16 + col16;
        af[mi] = *(const bf16x8*)((const char*)As_ + row * 128 + ((q ^ (row & 7)) * 16));
      }
#pragma unroll
      for (int ni = 0; ni < 4; ++ni) {
        int row = wc + ni * 16 + col16;
        bfr[ni] = *(const bf16x8*)((const char*)Bs_ + row * 128 + ((q ^ (row & 7)) * 16));
      }
#pragma unroll
      for (int mi = 0; mi < 4; ++mi)
#pragma unroll
        for (int ni = 0; ni < 4; ++ni)
          acc[mi][ni] = __builtin_amdgcn_mfma_f32_16x16x32_bf16(af[mi], bfr[ni], acc[mi][ni], 0, 0, 0);
    }
    __syncthreads();
    cur ^= 1;
  }

#pragma unroll
  for (int mi = 0; mi < 4; ++mi) {
#pragma unroll
    for (int r = 0; r < 4; ++r) {
      int gm = tm * 128 + wr + mi * 16 + rowg * 4 + r;
      if (gm >= M_) continue;
#pragma unroll
      for (int ni = 0; ni < 4; ++ni) {
        int gn = tn * 128 + wc + ni * 16 + col16;
        out[(size_t)gm * 768 + gn] = acc[mi][ni][r] + bias[gn];
      }
    }
  }
}

// ------------------------------------------------------------------ launch
extern "C" void kernel_launch(void* const* d_in, const int* in_sizes, int n_in,
                              void* d_out, int out_size, void* d_ws, size_t ws_size,
                              hipStream_t stream) {
  const float* x      = (const float*)d_in[0];
  const float* qkv_w  = (const float*)d_in[1];
  const float* qkv_b  = (const float*)d_in[2];
  const float* proj_w = (const float*)d_in[3];
  const float* proj_b = (const float*)d_in[4];
  const float* relpos = (const float*)d_in[5];
  const int*   rpidx  = (const int*)d_in[6];
  float* out = (float*)d_out;

  char* ws = (char*)d_ws;
  u16*   x16  = (u16*)(ws);                    // 19,464,192 B  [MPAD][768]
  u16*   wq16 = (u16*)(ws + 19464192);         //  3,538,944 B  [2304][768]
  u16*   wp16 = (u16*)(ws + 23003136);         //  1,179,648 B  [768][768]
  u16*   bb16 = (u16*)(ws + 24182784);         //    978,432 B  [12][196][208] bf16 (pre-scaled by log2e)
  u16*   q16  = (u16*)(ws + 25161216);         // 19,365,888 B  [B*H][197][64]
  u16*   k16  = (u16*)(ws + 44527104);         // 19,365,888 B  [B*H][197][64]
  u16*   vt16 = (u16*)(ws + 63892992);         // 22,020,096 B  [B*H][64][KP_]
  u16*   ao16 = (u16*)(ws + 85913088);         // 19,464,192 B  [MPAD][768]
  // total 105,377,280 B
  // vt16 pad keys (>=197) are never initialized: k_attn stages V into LDS
  // (keys 0..207 only) and zeroes keys 197..207 there; keys >=208 are never
  // read (dead-lane substitution in the PV loop).

  k_prep<<<7824, 256, 0, stream>>>(x, qkv_w, proj_w, relpos, rpidx,
                                   x16, wq16, wp16, bb16);
  k_gemm_qkv<<<99 * 18, 256, 0, stream>>>(x16, wq16, qkv_b, q16, k16, vt16);
  k_attn<<<768, 512, 0, stream>>>(q16, k16, vt16, bb16, ao16);
  k_gemm_proj<<<99 * 6, 256, 0, stream>>>(ao16, wp16, proj_b, out);
}